// Round 5
// baseline (293.125 us; speedup 1.0000x reference)
//
#include <hip/hip_runtime.h>
#include <stdint.h>

// Problem constants (match reference setup_inputs)
#define TOTAL  262144      // B*N = 16*16384
#define HALF   131072      // TOTAL/2 for threefry counter split
#define G      1024        // NUM_GROUPS
#define NBINS  1025        // groups 0..1023 + sentinel 1024 (masked)
#define NCHUNK 512         // chunks for counting sort
#define CHUNK  512         // elements per chunk

// workspace layout (bytes)
#define OFF_COUNTS 0               // int[1025]
#define OFF_STARTS 8192            // int[1025]
#define OFF_VT     16388           // int: valid_total
#define OFF_LOSS   16392           // double
#define OFF_VALID  16400           // double
#define OFF_TICKET 16408           // uint: last-block ticket
#define OFF_ORDER  16448           // int[TOTAL]
#define OFF_GHIST  1065024         // int[NBINS*NCHUNK]  (~2.1 MB), g-major
#define OFF_BF16   4194304         // bf16 table, 64 MB (TOTAL rows x 128 bf16)

// ---------------- threefry2x32 (JAX-compatible) ----------------
__device__ __forceinline__ void threefry2x32(uint32_t k0, uint32_t k1,
                                             uint32_t& x0, uint32_t& x1) {
  uint32_t ks0 = k0, ks1 = k1, ks2 = k0 ^ k1 ^ 0x1BD11BDAu;
#define TF_RND(R) { x0 += x1; x1 = (x1 << (R)) | (x1 >> (32 - (R))); x1 ^= x0; }
  x0 += ks0; x1 += ks1;
  TF_RND(13) TF_RND(15) TF_RND(26) TF_RND(6)
  x0 += ks1; x1 += ks2 + 1u;
  TF_RND(17) TF_RND(29) TF_RND(16) TF_RND(24)
  x0 += ks2; x1 += ks0 + 2u;
  TF_RND(13) TF_RND(15) TF_RND(26) TF_RND(6)
  x0 += ks0; x1 += ks1 + 3u;
  TF_RND(17) TF_RND(29) TF_RND(16) TF_RND(24)
  x0 += ks1; x1 += ks2 + 4u;
  TF_RND(13) TF_RND(15) TF_RND(26) TF_RND(6)
  x0 += ks2; x1 += ks0 + 5u;
#undef TF_RND
}

__device__ __forceinline__ int load_mask(const void* mask, int is8, int j) {
  return is8 ? (int)((const unsigned char*)mask)[j] : ((const int*)mask)[j];
}

// Per-wave self-detection of mask storage: int32 storage of 0/1 => all bytes
// at (addr%4)!=0 are zero. Probe bytes [0,256): 64 lanes x uchar4.
__device__ __forceinline__ int detect_is8(const void* mask) {
  int lane = threadIdx.x & 63;
  uchar4 p = ((const uchar4*)mask)[lane];
  unsigned long long bal = __ballot((p.y | p.z | p.w) != 0);
  return bal != 0ull;
}

// RNE float -> bf16
__device__ __forceinline__ uint32_t bf16rne(float f) {
  uint32_t u = __float_as_uint(f);
  return (u + 0x7FFFu + ((u >> 16) & 1u)) >> 16;
}
__device__ __forceinline__ uint32_t pack2(float lo, float hi) {
  return bf16rne(lo) | (bf16rne(hi) << 16);
}
// dot of 2 packed bf16 pairs in f32
__device__ __forceinline__ float dotu(uint32_t a, uint32_t b) {
  float alo = __uint_as_float(a << 16), ahi = __uint_as_float(a & 0xFFFF0000u);
  float blo = __uint_as_float(b << 16), bhi = __uint_as_float(b & 0xFFFF0000u);
  return alo * blo + ahi * bhi;
}
__device__ __forceinline__ float dot8(uint4 a, uint4 b) {
  return dotu(a.x, b.x) + dotu(a.y, b.y) + dotu(a.z, b.z) + dotu(a.w, b.w);
}

// K1: fused convert (f32 -> bf16 table) + per-chunk histogram.
// Block c: histogram of elements [c*512,(c+1)*512) and conversion of the
// same 512 rows (float4 [c*16384, (c+1)*16384)).
__global__ __launch_bounds__(512) void k_convhist(const float4* __restrict__ e4,
                                                  const int* __restrict__ groups,
                                                  const void* __restrict__ mask,
                                                  int* __restrict__ counts,
                                                  int* __restrict__ ghist,
                                                  uint4* __restrict__ bt) {
  __shared__ int h[NBINS];
  int t = threadIdx.x;
  int c = blockIdx.x;
  int is8 = detect_is8(mask);
  for (int b = t; b < NBINS; b += 512) h[b] = 0;
  __syncthreads();
  int j = c * CHUNK + t;
  int m = load_mask(mask, is8, j);
  int g = m ? groups[j] : G;
  atomicAdd(&h[g], 1);
  // convert 16384 float4 -> 8192 uint4 (each thread: 16 x {2 float4 -> 1 uint4})
  size_t base = (size_t)c * 16384;
#pragma unroll 4
  for (int k = 0; k < 16; k++) {
    size_t i4 = base + (size_t)k * 1024 + 2 * t;
    float4 f0 = e4[i4], f1 = e4[i4 + 1];
    uint4 o;
    o.x = pack2(f0.x, f0.y); o.y = pack2(f0.z, f0.w);
    o.z = pack2(f1.x, f1.y); o.w = pack2(f1.z, f1.w);
    bt[base / 2 + (size_t)k * 512 + t] = o;
  }
  __syncthreads();
  for (int b = t; b < NBINS; b += 512) {
    int v = h[b];
    ghist[b * NCHUNK + c] = v;
    if (v) atomicAdd(&counts[b], v);
  }
}

// K2: fused scan + rebase. Wave 0 of each block computes the full exclusive
// scan of counts into LDS (block 0 also publishes starts[] and vt); then each
// wave rebases one group's chunk row of ghist into global positions.
__global__ __launch_bounds__(256) void k_rebase(const int* __restrict__ counts,
                                                int* __restrict__ starts,
                                                int* __restrict__ vtp,
                                                int* __restrict__ ghist) {
  __shared__ int stl[NBINS];
  int t = threadIdx.x;
  int wave = t >> 6, lane = t & 63;
  if (wave == 0) {
    int cr[16];
    int s = 0;
#pragma unroll
    for (int k = 0; k < 16; k++) { cr[k] = counts[lane * 16 + k]; s += cr[k]; }
    int incl = s;
    for (int d = 1; d < 64; d <<= 1) {
      int tt = __shfl_up(incl, d);
      if (lane >= d) incl += tt;
    }
    int run = incl - s;
#pragma unroll
    for (int k = 0; k < 16; k++) {
      stl[lane * 16 + k] = run;
      if (blockIdx.x == 0) starts[lane * 16 + k] = run;
      run += cr[k];
    }
    if (lane == 63) {
      stl[1024] = run;
      if (blockIdx.x == 0) { starts[1024] = run; *vtp = run; }  // vt == #unmasked
    }
  }
  __syncthreads();
  int g = blockIdx.x * 4 + wave;
  if (g < NBINS) {
    int* row = ghist + g * NCHUNK;
    int v[8];
    int s = 0;
    int bi = lane * 8;
#pragma unroll
    for (int k = 0; k < 8; k++) { v[k] = row[bi + k]; s += v[k]; }
    int incl = s;
    for (int d = 1; d < 64; d <<= 1) {
      int tt = __shfl_up(incl, d);
      if (lane >= d) incl += tt;
    }
    int run = stl[g] + (incl - s);
#pragma unroll
    for (int k = 0; k < 8; k++) { int tt = v[k]; row[bi + k] = run; run += tt; }
  }
}

// K3: stable rank + scatter. Rank via 11-bit ballot match-any + per-wave
// leader counts in LDS.
__global__ __launch_bounds__(CHUNK) void k_scatter(const int* __restrict__ groups,
                                                   const void* __restrict__ mask,
                                                   const int* __restrict__ ghist,
                                                   int* __restrict__ order) {
  __shared__ int h[8][NBINS];          // 32.8 KB
  int t = threadIdx.x;
  int wave = t >> 6, lane = t & 63;
  int is8 = detect_is8(mask);
  int j = blockIdx.x * CHUNK + t;
  int m = load_mask(mask, is8, j);
  int g = m ? groups[j] : G;
  for (int idx = t; idx < 8 * NBINS; idx += CHUNK) ((int*)h)[idx] = 0;
  __syncthreads();
  unsigned long long mm = ~0ull;
#pragma unroll
  for (int b = 0; b < 11; b++) {
    unsigned long long bal = __ballot(((g >> b) & 1) != 0);
    mm &= ((g >> b) & 1) ? bal : ~bal;
  }
  unsigned long long lt = (1ull << lane) - 1ull;
  int lanerank = __popcll(mm & lt);
  if (lanerank == 0) h[wave][g] = __popcll(mm);   // unique (wave,g) writer
  __syncthreads();
  int rank = lanerank;
  for (int w = 0; w < wave; w++) rank += h[w][g];
  int pos = ghist[g * NCHUNK + blockIdx.x] + rank;
  order[pos] = j;
}

// K4: main. bf16-table gathers (256 B rows); tail blocks (all-masked) skip
// the gather work; last-block ticket computes the final loss (fused k_final).
__global__ __launch_bounds__(256) void k_main(const uint4* __restrict__ bt,
                                              const int* __restrict__ groups,
                                              const void* __restrict__ mask,
                                              const int* __restrict__ counts,
                                              const int* __restrict__ starts,
                                              const int* __restrict__ vtp,
                                              const int* __restrict__ order,
                                              double* __restrict__ lossAcc,
                                              double* __restrict__ validAcc,
                                              unsigned int* __restrict__ ticket,
                                              float* __restrict__ out) {
  __shared__ int mA[128], mP[128], mN[128], mF[128];
  __shared__ float bl[4], bv[4];
  int t = threadIdx.x;
  int wave = t >> 6, lane = t & 63;
  int vt = *vtp;
  int P0 = blockIdx.x * 128;

  if (P0 < vt) {
    int is8 = detect_is8(mask);
    // ---- Phase A: lanes 0..31 compute metadata
    if (lane < 32) {
      int i = P0 + wave * 32 + lane;
      int slot = wave * 32 + lane;
      if (i < vt) {
        int j = order[i];
        int mm2 = load_mask(mask, is8, j);
        int g = mm2 ? groups[j] : G;
        int cnt = counts[g], st = starts[g];
        int local = i - st;
        int partner_pos = (local == 0) ? (st + cnt - 1) : (i - 1);
        int pos_idx = order[partner_pos];

        uint32_t x0, x1;
        if (i < HALF) { x0 = (uint32_t)i; x1 = (uint32_t)(i + HALF); }
        else          { x0 = (uint32_t)(i - HALF); x1 = (uint32_t)i; }
        threefry2x32(0u, 42u, x0, x1);
        uint32_t bits = (i < HALF) ? x0 : x1;
        float u = __uint_as_float((bits >> 9) | 0x3F800000u) - 1.0f;

        int compi = vt - cnt;
        int comp = compi > 1 ? compi : 1;
        int r = (int)(u * (float)comp);
        int cm1 = comp - 1;
        if (r > cm1) r = cm1;
        int neg_pos = (r < st) ? r : (r + cnt);
        if (neg_pos < 0) neg_pos = 0;
        if (neg_pos > TOTAL - 1) neg_pos = TOTAL - 1;
        int neg_idx = order[neg_pos];
        int valid = (g < G) && (cnt >= 2) && (compi > 0);
        int shufok = (partner_pos == i - 1);

        mA[slot] = j; mP[slot] = pos_idx; mN[slot] = neg_idx;
        mF[slot] = valid | (shufok << 1);
      } else {
        mA[slot] = 0; mP[slot] = 0; mN[slot] = 0; mF[slot] = 0;
      }
    }
    __syncthreads();

    // ---- Phase B: 8 lanes per anchor; row = 16 uint4 (256 B bf16)
    int sg = lane >> 3, sl = lane & 7;
    float lsum = 0.f, vsum = 0.f;
#pragma unroll 1
    for (int it = 0; it < 4; it++) {
      int slot = wave * 32 + it * 8 + sg;
      int ai = mA[slot], pi = mP[slot], ni = mN[slot], fl = mF[slot];
      int ab = ai * 16 + sl * 2;
      int nb = ni * 16 + sl * 2;
      uint4 a0 = bt[ab], a1 = bt[ab + 1];
      uint4 n0 = bt[nb], n1 = bt[nb + 1];
      // positive fragment = neighbor lane-group's anchor fragment (packed)
      uint4 p0, p1;
      p0.x = __shfl_up(a0.x, 8); p0.y = __shfl_up(a0.y, 8);
      p0.z = __shfl_up(a0.z, 8); p0.w = __shfl_up(a0.w, 8);
      p1.x = __shfl_up(a1.x, 8); p1.y = __shfl_up(a1.y, 8);
      p1.z = __shfl_up(a1.z, 8); p1.w = __shfl_up(a1.w, 8);
      if (!((sg > 0) && (fl & 2))) {
        int pb = pi * 16 + sl * 2;
        p0 = bt[pb]; p1 = bt[pb + 1];
      }
      float ap = dot8(a0, p0) + dot8(a1, p1);
      float an = dot8(a0, n0) + dot8(a1, n1);
      ap += __shfl_xor(ap, 4); an += __shfl_xor(an, 4);
      ap += __shfl_xor(ap, 2); an += __shfl_xor(an, 2);
      ap += __shfl_xor(ap, 1); an += __shfl_xor(an, 1);
      if ((fl & 1) && sl == 0) {
        float ps = ap * 10.0f, ns = an * 10.0f;   // 1/TEMPERATURE
        float dd = ns - ps;
        float li = fmaxf(dd, 0.0f) + log1pf(expf(-fabsf(dd)));
        lsum += li; vsum += 1.0f;
      }
    }
    for (int d = 32; d >= 1; d >>= 1) {
      lsum += __shfl_xor(lsum, d);
      vsum += __shfl_xor(vsum, d);
    }
    if (lane == 0) { bl[wave] = lsum; bv[wave] = vsum; }
    __syncthreads();
    if (t == 0) {
      float L = bl[0] + bl[1] + bl[2] + bl[3];
      float V = bv[0] + bv[1] + bv[2] + bv[3];
      atomicAdd(lossAcc, (double)L);
      atomicAdd(validAcc, (double)V);
    }
  }

  // ---- fused finalize: last block (by ticket) computes out
  if (t == 0) {
    __threadfence();
    unsigned int old = atomicAdd(ticket, 1u);
    if (old == gridDim.x - 1) {
      double L = atomicAdd(lossAcc, 0.0);
      double V = atomicAdd(validAcc, 0.0);
      if (V < 1.0) V = 1.0;
      out[0] = (float)(L / V);
    }
  }
}

extern "C" void kernel_launch(void* const* d_in, const int* in_sizes, int n_in,
                              void* d_out, int out_size, void* d_ws, size_t ws_size,
                              hipStream_t stream) {
  const float* emb = (const float*)d_in[0];
  const int* groups = (const int*)d_in[1];
  const void* mask = d_in[2];
  float* out = (float*)d_out;

  char* ws = (char*)d_ws;
  int* counts = (int*)(ws + OFF_COUNTS);
  int* starts = (int*)(ws + OFF_STARTS);
  int* vt = (int*)(ws + OFF_VT);
  double* lossAcc = (double*)(ws + OFF_LOSS);
  double* validAcc = (double*)(ws + OFF_VALID);
  unsigned int* ticket = (unsigned int*)(ws + OFF_TICKET);
  int* order = (int*)(ws + OFF_ORDER);
  int* ghist = (int*)(ws + OFF_GHIST);
  uint4* bt = (uint4*)(ws + OFF_BF16);

  // zero counts + accumulators + ticket (ws is poisoned 0xAA before each launch)
  hipMemsetAsync(ws, 0, 16416, stream);

  k_convhist<<<NCHUNK, 512, 0, stream>>>((const float4*)emb, groups, mask,
                                         counts, ghist, bt);
  k_rebase<<<(NBINS + 3) / 4, 256, 0, stream>>>(counts, starts, vt, ghist);
  k_scatter<<<NCHUNK, CHUNK, 0, stream>>>(groups, mask, ghist, order);
  k_main<<<TOTAL / 128, 256, 0, stream>>>(bt, groups, mask, counts, starts,
                                          vt, order, lossAcc, validAcc,
                                          ticket, out);
}

// Round 7
// 289.664 us; speedup vs baseline: 1.0119x; 1.0119x over previous
//
#include <hip/hip_runtime.h>
#include <stdint.h>

// Problem constants (match reference setup_inputs)
#define TOTAL  262144      // B*N = 16*16384
#define HALF   131072      // TOTAL/2 for threefry counter split
#define G      1024        // NUM_GROUPS
#define NBINS  1025        // groups 0..1023 + sentinel 1024 (masked)
#define NCHUNK 512         // chunks for counting sort
#define CHUNK  512         // elements per chunk

// workspace layout (bytes)
#define OFF_COUNTS 0               // int[1025]
#define OFF_STARTS 8192            // int[1025]
#define OFF_VT     16388           // int: valid_total
#define OFF_LOSS   16392           // double
#define OFF_VALID  16400           // double
#define OFF_TICKET 16408           // uint: last-block ticket
#define OFF_SINK   16416           // float: prime DCE sink
#define OFF_ORDER  16448           // int[TOTAL]
#define OFF_GHIST  1065024         // int[NBINS*NCHUNK]  (~2.1 MB), g-major
#define OFF_BF16   4194304         // bf16 table, 64 MB (TOTAL rows x 128 bf16)

// ---------------- threefry2x32 (JAX-compatible) ----------------
__device__ __forceinline__ void threefry2x32(uint32_t k0, uint32_t k1,
                                             uint32_t& x0, uint32_t& x1) {
  uint32_t ks0 = k0, ks1 = k1, ks2 = k0 ^ k1 ^ 0x1BD11BDAu;
#define TF_RND(R) { x0 += x1; x1 = (x1 << (R)) | (x1 >> (32 - (R))); x1 ^= x0; }
  x0 += ks0; x1 += ks1;
  TF_RND(13) TF_RND(15) TF_RND(26) TF_RND(6)
  x0 += ks1; x1 += ks2 + 1u;
  TF_RND(17) TF_RND(29) TF_RND(16) TF_RND(24)
  x0 += ks2; x1 += ks0 + 2u;
  TF_RND(13) TF_RND(15) TF_RND(26) TF_RND(6)
  x0 += ks0; x1 += ks1 + 3u;
  TF_RND(17) TF_RND(29) TF_RND(16) TF_RND(24)
  x0 += ks1; x1 += ks2 + 4u;
  TF_RND(13) TF_RND(15) TF_RND(26) TF_RND(6)
  x0 += ks2; x1 += ks0 + 5u;
#undef TF_RND
}

__device__ __forceinline__ int load_mask(const void* mask, int is8, int j) {
  return is8 ? (int)((const unsigned char*)mask)[j] : ((const int*)mask)[j];
}

// Per-wave self-detection of mask storage: int32 storage of 0/1 => all bytes
// at (addr%4)!=0 are zero. Probe bytes [0,256): 64 lanes x uchar4.
__device__ __forceinline__ int detect_is8(const void* mask) {
  int lane = threadIdx.x & 63;
  uchar4 p = ((const uchar4*)mask)[lane];
  unsigned long long bal = __ballot((p.y | p.z | p.w) != 0);
  return bal != 0ull;
}

// RNE float -> bf16
__device__ __forceinline__ uint32_t bf16rne(float f) {
  uint32_t u = __float_as_uint(f);
  return (u + 0x7FFFu + ((u >> 16) & 1u)) >> 16;
}
__device__ __forceinline__ uint32_t pack2(float lo, float hi) {
  return bf16rne(lo) | (bf16rne(hi) << 16);
}
// dot of 2 packed bf16 pairs in f32
__device__ __forceinline__ float dotu(uint32_t a, uint32_t b) {
  float alo = __uint_as_float(a << 16), ahi = __uint_as_float(a & 0xFFFF0000u);
  float blo = __uint_as_float(b << 16), bhi = __uint_as_float(b & 0xFFFF0000u);
  return alo * blo + ahi * bhi;
}
__device__ __forceinline__ float dot8(uint4 a, uint4 b) {
  return dotu(a.x, b.x) + dotu(a.y, b.y) + dotu(a.z, b.z) + dotu(a.w, b.w);
}

// K1: fused convert (f32 -> bf16 table, valid rows only) + per-chunk histogram.
__global__ __launch_bounds__(512) void k_convhist(const float4* __restrict__ e4,
                                                  const int* __restrict__ groups,
                                                  const void* __restrict__ mask,
                                                  int* __restrict__ counts,
                                                  int* __restrict__ ghist,
                                                  uint4* __restrict__ bt) {
  __shared__ int h[NBINS];
  __shared__ unsigned char sm[CHUNK];
  int t = threadIdx.x;
  int c = blockIdx.x;
  int is8 = detect_is8(mask);
  for (int b = t; b < NBINS; b += 512) h[b] = 0;
  __syncthreads();
  int j = c * CHUNK + t;
  int m = load_mask(mask, is8, j);
  int g = m ? groups[j] : G;
  sm[t] = (unsigned char)(m != 0);
  atomicAdd(&h[g], 1);
  __syncthreads();
  // convert: 16384 float4 -> 8192 uint4; skip masked rows (never gathered).
  size_t base = (size_t)c * 16384;
#pragma unroll 4
  for (int k = 0; k < 16; k++) {
    int row_local = k * 32 + (t >> 4);     // which of the 512 rows this elt is in
    if (sm[row_local]) {
      size_t i4 = base + (size_t)k * 1024 + 2 * t;
      float4 f0 = e4[i4], f1 = e4[i4 + 1];
      uint4 o;
      o.x = pack2(f0.x, f0.y); o.y = pack2(f0.z, f0.w);
      o.z = pack2(f1.x, f1.y); o.w = pack2(f1.z, f1.w);
      bt[base / 2 + (size_t)k * 512 + t] = o;
    }
  }
  for (int b = t; b < NBINS; b += 512) {
    int v = h[b];
    ghist[b * NCHUNK + c] = v;
    if (v) atomicAdd(&counts[b], v);
  }
}

// K2: fused scan + rebase. Wave 0 of each block computes the full exclusive
// scan of counts into LDS (block 0 also publishes starts[] and vt); then each
// wave rebases one group's chunk row of ghist into global positions.
__global__ __launch_bounds__(256) void k_rebase(const int* __restrict__ counts,
                                                int* __restrict__ starts,
                                                int* __restrict__ vtp,
                                                int* __restrict__ ghist) {
  __shared__ int stl[NBINS];
  int t = threadIdx.x;
  int wave = t >> 6, lane = t & 63;
  if (wave == 0) {
    int cr[16];
    int s = 0;
#pragma unroll
    for (int k = 0; k < 16; k++) { cr[k] = counts[lane * 16 + k]; s += cr[k]; }
    int incl = s;
    for (int d = 1; d < 64; d <<= 1) {
      int tt = __shfl_up(incl, d);
      if (lane >= d) incl += tt;
    }
    int run = incl - s;
#pragma unroll
    for (int k = 0; k < 16; k++) {
      stl[lane * 16 + k] = run;
      if (blockIdx.x == 0) starts[lane * 16 + k] = run;
      run += cr[k];
    }
    if (lane == 63) {
      stl[1024] = run;
      if (blockIdx.x == 0) { starts[1024] = run; *vtp = run; }  // vt == #unmasked
    }
  }
  __syncthreads();
  int g = blockIdx.x * 4 + wave;
  if (g < NBINS) {
    int* row = ghist + g * NCHUNK;
    int v[8];
    int s = 0;
    int bi = lane * 8;
#pragma unroll
    for (int k = 0; k < 8; k++) { v[k] = row[bi + k]; s += v[k]; }
    int incl = s;
    for (int d = 1; d < 64; d <<= 1) {
      int tt = __shfl_up(incl, d);
      if (lane >= d) incl += tt;
    }
    int run = stl[g] + (incl - s);
#pragma unroll
    for (int k = 0; k < 8; k++) { int tt = v[k]; row[bi + k] = run; run += tt; }
  }
}

// K3: stable rank + scatter (ballot match-any), then PRIME: grid-stride read
// of the bf16 table so it allocates in the memory-side Infinity Cache
// (writes don't allocate -- R5 evidence: 40 MB re-fetch in k_main).
__global__ __launch_bounds__(CHUNK) void k_scatter(const int* __restrict__ groups,
                                                   const void* __restrict__ mask,
                                                   const int* __restrict__ ghist,
                                                   int* __restrict__ order,
                                                   const uint4* __restrict__ bt,
                                                   float* __restrict__ sink) {
  __shared__ int h[8][NBINS];          // 32.8 KB
  int t = threadIdx.x;
  int wave = t >> 6, lane = t & 63;
  int is8 = detect_is8(mask);
  int j = blockIdx.x * CHUNK + t;
  int m = load_mask(mask, is8, j);
  int g = m ? groups[j] : G;
  for (int idx = t; idx < 8 * NBINS; idx += CHUNK) ((int*)h)[idx] = 0;
  __syncthreads();
  unsigned long long mm = ~0ull;
#pragma unroll
  for (int b = 0; b < 11; b++) {
    unsigned long long bal = __ballot(((g >> b) & 1) != 0);
    mm &= ((g >> b) & 1) ? bal : ~bal;
  }
  unsigned long long lt = (1ull << lane) - 1ull;
  int lanerank = __popcll(mm & lt);
  if (lanerank == 0) h[wave][g] = __popcll(mm);   // unique (wave,g) writer
  __syncthreads();
  int rank = lanerank;
  for (int w = 0; w < wave; w++) rank += h[w][g];
  int pos = ghist[g * NCHUNK + blockIdx.x] + rank;
  order[pos] = j;

  // ---- L3 prime: stream the 64 MB bf16 table (read-allocate)
  size_t n4 = (size_t)TOTAL * 16;          // 4M uint4
  float acc = 0.f;
  for (size_t idx = (size_t)blockIdx.x * CHUNK + t; idx < n4;
       idx += (size_t)gridDim.x * CHUNK) {
    uint4 v = bt[idx];
    acc += (float)(v.x ^ v.y ^ v.z ^ v.w);
  }
  if (acc == 1.2345678e18f) sink[0] = acc;   // keeps loads live, never taken
}

// K4: main. 4 lanes per anchor, anchor-pairs per lane group:
//   slot0 (even pos) + slot1 (odd pos). pos-partner of slot1 == anchor slot0
//   (same-lane registers); pos-partner of slot0 == neighbor group's slot1
//   (shfl_up 4). 16 uint4 gathers issued back-to-back per lane (MLP).
__global__ __launch_bounds__(256) void k_main(const uint4* __restrict__ bt,
                                              const int* __restrict__ groups,
                                              const void* __restrict__ mask,
                                              const int* __restrict__ counts,
                                              const int* __restrict__ starts,
                                              const int* __restrict__ vtp,
                                              const int* __restrict__ order,
                                              double* __restrict__ lossAcc,
                                              double* __restrict__ validAcc,
                                              unsigned int* __restrict__ ticket,
                                              float* __restrict__ out) {
  __shared__ int mA[128], mP[128], mN[128], mF[128];
  __shared__ float bl[4], bv[4];
  int t = threadIdx.x;
  int wave = t >> 6, lane = t & 63;
  int vt = *vtp;
  int P0 = blockIdx.x * 128;

  if (P0 < vt) {
    int is8 = detect_is8(mask);
    // ---- Phase A: lanes 0..31 compute metadata
    if (lane < 32) {
      int i = P0 + wave * 32 + lane;
      int slot = wave * 32 + lane;
      if (i < vt) {
        int j = order[i];
        int mm2 = load_mask(mask, is8, j);
        int g = mm2 ? groups[j] : G;
        int cnt = counts[g], st = starts[g];
        int local = i - st;
        int partner_pos = (local == 0) ? (st + cnt - 1) : (i - 1);
        int pos_idx = order[partner_pos];

        uint32_t x0, x1;
        if (i < HALF) { x0 = (uint32_t)i; x1 = (uint32_t)(i + HALF); }
        else          { x0 = (uint32_t)(i - HALF); x1 = (uint32_t)i; }
        threefry2x32(0u, 42u, x0, x1);
        uint32_t bits = (i < HALF) ? x0 : x1;
        float u = __uint_as_float((bits >> 9) | 0x3F800000u) - 1.0f;

        int compi = vt - cnt;
        int comp = compi > 1 ? compi : 1;
        int r = (int)(u * (float)comp);
        int cm1 = comp - 1;
        if (r > cm1) r = cm1;
        int neg_pos = (r < st) ? r : (r + cnt);
        if (neg_pos < 0) neg_pos = 0;
        if (neg_pos > TOTAL - 1) neg_pos = TOTAL - 1;
        int neg_idx = order[neg_pos];
        int valid = (g < G) && (cnt >= 2) && (compi > 0);
        int shufok = (partner_pos == i - 1);

        mA[slot] = j; mP[slot] = pos_idx; mN[slot] = neg_idx;
        mF[slot] = valid | (shufok << 1);
      } else {
        mA[slot] = 0; mP[slot] = 0; mN[slot] = 0; mF[slot] = 0;
      }
    }
    __syncthreads();

    // ---- Phase B: 4 lanes x (anchor pair)
    int sg = lane >> 2, sl = lane & 3;
    int slot0 = wave * 32 + (sg << 1);
    int slot1 = slot0 + 1;
    int a0i = mA[slot0], n0i = mN[slot0], f0 = mF[slot0];
    int a1i = mA[slot1], n1i = mN[slot1], f1 = mF[slot1];
    uint4 A0[4], A1[4], N0[4], N1[4];
    {
      int ab0 = a0i * 16 + sl * 4;
      int ab1 = a1i * 16 + sl * 4;
      int nb0 = n0i * 16 + sl * 4;
      int nb1 = n1i * 16 + sl * 4;
#pragma unroll
      for (int k = 0; k < 4; k++) {
        A0[k] = bt[ab0 + k];
        A1[k] = bt[ab1 + k];
        N0[k] = bt[nb0 + k];
        N1[k] = bt[nb1 + k];
      }
    }
    // positives
    uint4 Pv0[4], Pv1[4];
#pragma unroll
    for (int k = 0; k < 4; k++) {
      Pv0[k].x = __shfl_up(A1[k].x, 4);
      Pv0[k].y = __shfl_up(A1[k].y, 4);
      Pv0[k].z = __shfl_up(A1[k].z, 4);
      Pv0[k].w = __shfl_up(A1[k].w, 4);
    }
    if (!((sg > 0) && (f0 & 2))) {
      int pb = mP[slot0] * 16 + sl * 4;
#pragma unroll
      for (int k = 0; k < 4; k++) Pv0[k] = bt[pb + k];
    }
    if (f1 & 2) {
#pragma unroll
      for (int k = 0; k < 4; k++) Pv1[k] = A0[k];
    } else {
      int pb = mP[slot1] * 16 + sl * 4;
#pragma unroll
      for (int k = 0; k < 4; k++) Pv1[k] = bt[pb + k];
    }
    float ap0 = 0.f, an0 = 0.f, ap1 = 0.f, an1 = 0.f;
#pragma unroll
    for (int k = 0; k < 4; k++) {
      ap0 += dot8(A0[k], Pv0[k]);
      an0 += dot8(A0[k], N0[k]);
      ap1 += dot8(A1[k], Pv1[k]);
      an1 += dot8(A1[k], N1[k]);
    }
    ap0 += __shfl_xor(ap0, 2); an0 += __shfl_xor(an0, 2);
    ap1 += __shfl_xor(ap1, 2); an1 += __shfl_xor(an1, 2);
    ap0 += __shfl_xor(ap0, 1); an0 += __shfl_xor(an0, 1);
    ap1 += __shfl_xor(ap1, 1); an1 += __shfl_xor(an1, 1);

    float lsum = 0.f, vsum = 0.f;
    if (sl == 0) {
      if (f0 & 1) {
        float dd = (an0 - ap0) * 10.0f;
        lsum += fmaxf(dd, 0.0f) + log1pf(expf(-fabsf(dd)));
        vsum += 1.0f;
      }
      if (f1 & 1) {
        float dd = (an1 - ap1) * 10.0f;
        lsum += fmaxf(dd, 0.0f) + log1pf(expf(-fabsf(dd)));
        vsum += 1.0f;
      }
    }
    for (int d = 32; d >= 1; d >>= 1) {
      lsum += __shfl_xor(lsum, d);
      vsum += __shfl_xor(vsum, d);
    }
    if (lane == 0) { bl[wave] = lsum; bv[wave] = vsum; }
    __syncthreads();
    if (t == 0) {
      float L = bl[0] + bl[1] + bl[2] + bl[3];
      float V = bv[0] + bv[1] + bv[2] + bv[3];
      atomicAdd(lossAcc, (double)L);
      atomicAdd(validAcc, (double)V);
    }
  }

  // ---- fused finalize: last block (by ticket) computes out
  if (t == 0) {
    __threadfence();
    unsigned int old = atomicAdd(ticket, 1u);
    if (old == gridDim.x - 1) {
      double L = atomicAdd(lossAcc, 0.0);
      double V = atomicAdd(validAcc, 0.0);
      if (V < 1.0) V = 1.0;
      out[0] = (float)(L / V);
    }
  }
}

extern "C" void kernel_launch(void* const* d_in, const int* in_sizes, int n_in,
                              void* d_out, int out_size, void* d_ws, size_t ws_size,
                              hipStream_t stream) {
  const float* emb = (const float*)d_in[0];
  const int* groups = (const int*)d_in[1];
  const void* mask = d_in[2];
  float* out = (float*)d_out;

  char* ws = (char*)d_ws;
  int* counts = (int*)(ws + OFF_COUNTS);
  int* starts = (int*)(ws + OFF_STARTS);
  int* vt = (int*)(ws + OFF_VT);
  double* lossAcc = (double*)(ws + OFF_LOSS);
  double* validAcc = (double*)(ws + OFF_VALID);
  unsigned int* ticket = (unsigned int*)(ws + OFF_TICKET);
  float* sink = (float*)(ws + OFF_SINK);
  int* order = (int*)(ws + OFF_ORDER);
  int* ghist = (int*)(ws + OFF_GHIST);
  uint4* bt = (uint4*)(ws + OFF_BF16);

  // zero counts + accumulators + ticket (ws is poisoned 0xAA before each launch)
  hipMemsetAsync(ws, 0, 16432, stream);

  k_convhist<<<NCHUNK, 512, 0, stream>>>((const float4*)emb, groups, mask,
                                         counts, ghist, bt);
  k_rebase<<<(NBINS + 3) / 4, 256, 0, stream>>>(counts, starts, vt, ghist);
  k_scatter<<<NCHUNK, CHUNK, 0, stream>>>(groups, mask, ghist, order, bt, sink);
  k_main<<<TOTAL / 128, 256, 0, stream>>>(bt, groups, mask, counts, starts,
                                          vt, order, lossAcc, validAcc,
                                          ticket, out);
}